// Round 2
// baseline (290.326 us; speedup 1.0000x reference)
//
#include <hip/hip_runtime.h>
#include <hip/hip_bf16.h>
#include <math.h>

#define N 256
#define D 768
#define BATCH 128

typedef float f32x4 __attribute__((ext_vector_type(4)));
typedef short bf16x8 __attribute__((ext_vector_type(8)));

// RNE fp32 -> bf16 (no NaN inputs in this problem)
static __device__ __forceinline__ unsigned short f2bf(float f) {
    unsigned int u = __float_as_uint(f);
    u += 0x7fffu + ((u >> 16) & 1u);
    return (unsigned short)(u >> 16);
}
static __device__ __forceinline__ unsigned int pack2bf(float lo, float hi) {
    unsigned int a = __float_as_uint(lo);
    unsigned int b = __float_as_uint(hi);
    a += 0x7fffu + ((a >> 16) & 1u);
    b += 0x7fffu + ((b >> 16) & 1u);
    return (a >> 16) | (b & 0xffff0000u);
}

// ---------------- Stage 1 (fused): norm (512 blk) + a2 (96 blk) + topk (64 blk)
__global__ void k_stage1(const float* __restrict__ cf, const float* __restrict__ ctx,
                         float* __restrict__ vsn, float* __restrict__ csn,
                         const float* __restrict__ w1, float* __restrict__ a,
                         const int* __restrict__ co, float* __restrict__ topv,
                         int* __restrict__ topi) {
    __shared__ float sm[2 * 64 * 33];        // union: norm red[256] / a2 Ci+Wj
    int bx = blockIdx.x;
    int t = threadIdx.x;                     // 256
    if (bx < 512) {
        // ---- norm ----
        int row = bx;
        const float* src;
        float* dst;
        if (row < N) { src = cf  + row * D;       dst = vsn + row * D; }
        else         { src = ctx + (row - N) * D; dst = csn + (row - N) * D; }
        float s = 0.f;
        for (int d = t; d < D; d += 256) { float v = src[d]; s += v * v; }
        float* red = sm;
        red[t] = s; __syncthreads();
        for (int off = 128; off > 0; off >>= 1) {
            if (t < off) red[t] += red[t + off];
            __syncthreads();
        }
        float inv = 1.0f / sqrtf(red[0]);
        for (int d = t; d < D; d += 256) dst[d] = src[d] * inv;
    } else if (bx < 608) {
        // ---- a = cf @ w1, 32x32 tiles ----
        int bi = bx - 512;
        int i0 = (bi / 12) * 32, j0 = (bi % 12) * 32;
        float (*Ci)[33] = (float(*)[33])sm;
        float (*Wj)[33] = (float(*)[33])(sm + 64 * 33);
        int tx = t & 15, ty = t >> 4;
        float a00 = 0.f, a01 = 0.f, a10 = 0.f, a11 = 0.f;
        for (int k0 = 0; k0 < 768; k0 += 64) {
            #pragma unroll
            for (int s = 0; s < 8; s++) {
                int idx = s * 256 + t;
                int row = idx >> 6, kc = idx & 63;
                Ci[kc][row] = cf[(i0 + row) * 768 + k0 + kc];
                int kr = idx >> 5, col = idx & 31;
                Wj[kr][col] = w1[(k0 + kr) * 384 + j0 + col];
            }
            __syncthreads();
            #pragma unroll 4
            for (int kk = 0; kk < 64; kk++) {
                float iv0 = Ci[kk][ty * 2], iv1 = Ci[kk][ty * 2 + 1];
                float jv0 = Wj[kk][tx * 2], jv1 = Wj[kk][tx * 2 + 1];
                a00 += iv0 * jv0; a01 += iv0 * jv1;
                a10 += iv1 * jv0; a11 += iv1 * jv1;
            }
            __syncthreads();
        }
        a[(i0 + ty * 2)     * 384 + j0 + tx * 2]     = a00;
        a[(i0 + ty * 2)     * 384 + j0 + tx * 2 + 1] = a01;
        a[(i0 + ty * 2 + 1) * 384 + j0 + tx * 2]     = a10;
        a[(i0 + ty * 2 + 1) * 384 + j0 + tx * 2 + 1] = a11;
    } else {
        // ---- top-5, one wave per row ----
        int lane = t & 63;
        int row = (bx - 608) * 4 + (t >> 6);
        int4 v4 = *(const int4*)(co + row * 256 + lane * 4);
        int key[4];
        key[0] = v4.x * 256 + (255 - (lane * 4 + 0));
        key[1] = v4.y * 256 + (255 - (lane * 4 + 1));
        key[2] = v4.z * 256 + (255 - (lane * 4 + 2));
        key[3] = v4.w * 256 + (255 - (lane * 4 + 3));
        for (int r = 0; r < 5; r++) {
            int best = key[0];
            #pragma unroll
            for (int e = 1; e < 4; e++) best = max(best, key[e]);
            #pragma unroll
            for (int off = 32; off > 0; off >>= 1) best = max(best, __shfl_xor(best, off, 64));
            int kidx = 255 - (best & 255);
            int val = best >> 8;
            if (lane == 0) { topv[row * 5 + r] = (float)val; topi[row * 5 + r] = kidx; }
            if ((kidx >> 2) == lane) key[kidx & 3] = -1;
        }
    }
}

// ---------------- K3: vs/cs gram, coalesced LDS-tiled (32x32 tiles) ---------
__global__ void k_gram2(const float* __restrict__ vsn, const float* __restrict__ csn,
                        float* __restrict__ vs, float* __restrict__ cs) {
    int bx = blockIdx.x;                 // 0..127
    const float* S = (bx >= 64) ? csn : vsn;
    float* O       = (bx >= 64) ? cs  : vs;
    int bi = bx & 63;
    int i0 = (bi >> 3) * 32, j0 = (bi & 7) * 32;
    __shared__ float Li[64][33], Lj[64][33];
    int t = threadIdx.x;
    int tx = t & 15, ty = t >> 4;
    float a00 = 0.f, a01 = 0.f, a10 = 0.f, a11 = 0.f;
    for (int k0 = 0; k0 < 768; k0 += 64) {
        #pragma unroll
        for (int s = 0; s < 8; s++) {
            int idx = s * 256 + t;
            int row = idx >> 6, kc = idx & 63;
            Li[kc][row] = S[(i0 + row) * 768 + k0 + kc];
            Lj[kc][row] = S[(j0 + row) * 768 + k0 + kc];
        }
        __syncthreads();
        #pragma unroll 4
        for (int kk = 0; kk < 64; kk++) {
            float iv0 = Li[kk][ty * 2], iv1 = Li[kk][ty * 2 + 1];
            float jv0 = Lj[kk][tx * 2], jv1 = Lj[kk][tx * 2 + 1];
            a00 += iv0 * jv0; a01 += iv0 * jv1;
            a10 += iv1 * jv0; a11 += iv1 * jv1;
        }
        __syncthreads();
    }
    O[(i0 + ty * 2)     * 256 + j0 + tx * 2]     = a00;
    O[(i0 + ty * 2)     * 256 + j0 + tx * 2 + 1] = a01;
    O[(i0 + ty * 2 + 1) * 256 + j0 + tx * 2]     = a10;
    O[(i0 + ty * 2 + 1) * 256 + j0 + tx * 2 + 1] = a11;
}

// ---------------- Stage 3 (fused): e1t (256 blk) + shared2 (64 blk) --------
__global__ void k_stage3(const float* __restrict__ a, const float* __restrict__ b1,
                         const float* __restrict__ w2, const float* __restrict__ b2,
                         const float* __restrict__ vs, const float* __restrict__ cs,
                         const int* __restrict__ ic, float* __restrict__ e1,
                         const int* __restrict__ co, float* __restrict__ ss,
                         float* __restrict__ sc) {
    __shared__ float sm[12800];          // 51200 B: e1t ai/ajm/sw2 OR shared2 tiles
    int bx = blockIdx.x;
    int t = threadIdx.x;
    if (bx < 256) {
        // ---- e1 pair-tiled 16x16 ----
        int i0 = (bx >> 4) * 16, j0 = (bx & 15) * 16;
        float (*ai)[388]  = (float(*)[388])sm;
        float (*ajm)[388] = (float(*)[388])(sm + 16 * 388);
        float* sw2 = sm + 2 * 16 * 388;
        for (int idx = t; idx < 16 * 96; idx += 256) {
            int r = idx / 96, c = (idx % 96) * 4;
            *(float4*)&ai[r][c] = *(const float4*)(a + (i0 + r) * 384 + c);
            float4 u  = *(const float4*)(a + (j0 + r) * 384 + c);
            float4 bb = *(const float4*)(b1 + c);
            u.x -= bb.x; u.y -= bb.y; u.z -= bb.z; u.w -= bb.w;
            *(float4*)&ajm[r][c] = u;
        }
        for (int k = t; k < 384; k += 256) sw2[k] = w2[k];
        __syncthreads();
        int tx = t & 15, ty = t >> 4;
        float s = 0.f;
        #pragma unroll 4
        for (int k4 = 0; k4 < 96; k4++) {
            float4 xv = *(const float4*)&ai[ty][k4 * 4];
            float4 yv = *(const float4*)&ajm[tx][k4 * 4];
            float4 wv = *(const float4*)&sw2[k4 * 4];
            s += fmaxf(xv.x - yv.x, 0.f) * wv.x;
            s += fmaxf(xv.y - yv.y, 0.f) * wv.y;
            s += fmaxf(xv.z - yv.z, 0.f) * wv.z;
            s += fmaxf(xv.w - yv.w, 0.f) * wv.w;
        }
        int i = i0 + ty, j = j0 + tx;
        float sig = 1.0f / (1.0f + expf(-(s + b2[0])));
        float comb = 0.7f * vs[i * 256 + j] + 0.3f * cs[i * 256 + j];
        float ci = (float)ic[i], cj = (float)ic[j];
        float mn = fminf(ci, cj), mx = fmaxf(ci, cj);
        float ratio = mn / fmaxf(mx, 1.0f);
        e1[i * 256 + j] = comb * sig * ratio;
    } else {
        // ---- shared_sum/cnt 32x32 tiles ----
        int bi = bx - 256;
        int i0 = (bi >> 3) * 32, j0 = (bi & 7) * 32;
        float (*Mi)[33] = (float(*)[33])sm;
        float (*Ai)[33] = (float(*)[33])(sm + 2112);
        float (*Mj)[33] = (float(*)[33])(sm + 4224);
        float (*Aj)[33] = (float(*)[33])(sm + 6336);
        int tx = t & 15, ty = t >> 4;
        float s00=0.f,s01=0.f,s10=0.f,s11=0.f;
        float c00=0.f,c01=0.f,c10=0.f,c11=0.f;
        for (int k0 = 0; k0 < 256; k0 += 64) {
            #pragma unroll
            for (int s = 0; s < 8; s++) {
                int idx = s * 256 + t;
                int row = idx >> 6, kc = idx & 63;
                int civ = co[(i0 + row) * 256 + k0 + kc];
                float aa = civ > 50 ? 1.f : 0.f;
                Ai[kc][row] = aa;
                Mi[kc][row] = aa * vs[(i0 + row) * 256 + k0 + kc];
                int cjv = co[(j0 + row) * 256 + k0 + kc];
                float ab = cjv > 50 ? 1.f : 0.f;
                Aj[kc][row] = ab;
                Mj[kc][row] = ab * vs[(j0 + row) * 256 + k0 + kc];
            }
            __syncthreads();
            #pragma unroll 4
            for (int kk = 0; kk < 64; kk++) {
                float mi0 = Mi[kk][ty*2], mi1 = Mi[kk][ty*2+1];
                float ai0 = Ai[kk][ty*2], ai1 = Ai[kk][ty*2+1];
                float mj0 = Mj[kk][tx*2], mj1 = Mj[kk][tx*2+1];
                float aj0 = Aj[kk][tx*2], aj1 = Aj[kk][tx*2+1];
                s00 += mi0*mj0; s01 += mi0*mj1; s10 += mi1*mj0; s11 += mi1*mj1;
                c00 += ai0*aj0; c01 += ai0*aj1; c10 += ai1*aj0; c11 += ai1*aj1;
            }
            __syncthreads();
        }
        ss[(i0+ty*2)  *256 + j0+tx*2]   = s00; ss[(i0+ty*2)  *256 + j0+tx*2+1] = s01;
        ss[(i0+ty*2+1)*256 + j0+tx*2]   = s10; ss[(i0+ty*2+1)*256 + j0+tx*2+1] = s11;
        sc[(i0+ty*2)  *256 + j0+tx*2]   = c00; sc[(i0+ty*2)  *256 + j0+tx*2+1] = c01;
        sc[(i0+ty*2+1)*256 + j0+tx*2]   = c10; sc[(i0+ty*2+1)*256 + j0+tx*2+1] = c11;
    }
}

// ---------------- K7: assemble E (tiered), zero diag, per-row max -----------
__global__ void k_assemble(const int* __restrict__ co, const float* __restrict__ vs,
                           const float* __restrict__ cs, const float* __restrict__ e1,
                           const float* __restrict__ ss, const float* __restrict__ sc,
                           const float* __restrict__ topv, const int* __restrict__ topi,
                           float* __restrict__ E, float* __restrict__ partials) {
    int i = blockIdx.x, j = threadIdx.x;
    int cij = co[i * 256 + j];
    float e;
    if (i == j) {
        e = 0.f;
    } else if (cij > 50) {
        e = e1[i * 256 + j];
    } else if (cij > 10) {
        float conf = (float)cij / 50.0f;
        float comb = 0.7f * vs[i * 256 + j] + 0.3f * cs[i * 256 + j];
        float cnt = sc[i * 256 + j];
        float avg = ss[i * 256 + j] / fmaxf(cnt, 1.f);
        e = (cnt > 0.f) ? conf * comb + (1.f - conf) * avg : conf * comb;
    } else {
        float tvi[5], tvj[5]; int tii[5], tij[5];
        #pragma unroll
        for (int k = 0; k < 5; k++) {
            tvi[k] = topv[i * 5 + k]; tii[k] = topi[i * 5 + k];
            tvj[k] = topv[j * 5 + k]; tij[k] = topi[j * 5 + k];
        }
        float trans = 0.f, tot = 0.f;
        #pragma unroll
        for (int k = 0; k < 5; k++) {
            if (!(tvi[k] > 10.f)) continue;
            float vin_i = vs[i * 256 + tii[k]];
            #pragma unroll
            for (int l = 0; l < 5; l++) {
                if (!(tvj[l] > 10.f)) continue;
                int cc = co[tii[k] * 256 + tij[l]];
                if (cc <= 0) continue;
                float w = tvi[k] * tvj[l] / 50.f;
                float sim = vin_i * vs[j * 256 + tij[l]] * vs[tii[k] * 256 + tij[l]];
                trans += w * sim; tot += w;
            }
        }
        e = (tot > 0.f) ? trans / tot : 0.1f * cs[i * 256 + j];
    }
    E[i * 256 + j] = e;
    __shared__ float red[256];
    red[j] = e; __syncthreads();
    for (int off = 128; off > 0; off >>= 1) {
        if (j < off) red[j] = fmaxf(red[j], red[j + off]);
        __syncthreads();
    }
    if (j == 0) partials[i] = red[0];
}

// ---------------- K8: Ep = bf16(I + s*E), s = 1/max (fused scale) -----------
__global__ void k_ep(const float* __restrict__ E, const float* __restrict__ partials,
                     unsigned short* __restrict__ Ep) {
    __shared__ float red[256];
    int t = threadIdx.x;
    red[t] = partials[t]; __syncthreads();
    for (int off = 128; off > 0; off >>= 1) {
        if (t < off) red[t] = fmaxf(red[t], red[t + off]);
        __syncthreads();
    }
    float mx = red[0];
    float s = (mx > 0.f) ? 1.0f / mx : 1.0f;
    int base = (blockIdx.x * 256 + t) * 4;
    float4 e4 = *(const float4*)(E + base);
    float ev[4] = {e4.x, e4.y, e4.z, e4.w};
    unsigned short o[4];
    #pragma unroll
    for (int q = 0; q < 4; q++) {
        int g = base + q;
        float v = s * ev[q] + (((g >> 8) == (g & 255)) ? 1.0f : 0.0f);
        o[q] = f2bf(v);
    }
    uint2 w;
    w.x = (unsigned int)o[0] | ((unsigned int)o[1] << 16);
    w.y = (unsigned int)o[2] | ((unsigned int)o[3] << 16);
    *(uint2*)(Ep + base) = w;
}

// ---------------- K9: out[b,:,dtile] = Ep @ x[b,:,dtile]  (bf16 MFMA) -------
// D[m=d][n=i] operand swap -> float4 output stores; x staged d-contiguous
// (float4 global loads, bank-dense b64 LDS writes) into subtiled layout
// [dblk(592e)][kblk(72e)][4k][16d]; A-frags via ds_read_b64_tr_b16.
// tr_b16 semantics (m156/m162): each lane fetches 8B at ITS OWN address;
// the 16-lane group's fetches concatenate (lane order) into 64 bf16 elems;
// lane c receives flat {c, c+16, c+32, c+48} = column c of the 4x16 subtile.
// => lane c must point at subtile elements [4c,4c+3]: addr = base + c*8.
//    (r1 bug: c*2 — element-indexed — scrambled A-frags.)
// Ep B-frags straight from global (128KB, L2-resident). LDS 18.9KB dbuf,
// 2 blocks/CU; one barrier per k-tile; prefetch issued after the barrier.
#define EINS_BUFB 9472   // bytes per k-tile buffer: 8 dblk * 592 elems * 2B

#define EIN_BODY(KT, BB, bvC, bvN)                                              \
  {                                                                             \
    _Pragma("unroll")                                                           \
    for (int s = 0; s < 4; s++) {                                               \
      uint2 pv;                                                                 \
      pv.x = pack2bf(xr[s].x, xr[s].y);                                         \
      pv.y = pack2bf(xr[s].z, xr[s].w);                                         \
      *(uint2*)((char*)xs + (BB) + wbyte + s * 32) = pv;                        \
    }                                                                           \
    __syncthreads();                                                            \
    if ((KT) < 7) {                                                             \
      const float* xn = xb + (size_t)((KT) + 1) * 32 * 768;                     \
      _Pragma("unroll")                                                         \
      for (int s = 0; s < 4; s++)                                               \
        xr[s] = *(const float4*)(xn + (size_t)(jb + s) * 768);                  \
      _Pragma("unroll")                                                         \
      for (int nf = 0; nf < 4; nf++)                                            \
        bvN[nf] = *(const uint4*)(eprow + (nf << 12) + ((KT) + 1) * 32);        \
    }                                                                           \
    uint2 a0[8], a1[8];                                                         \
    _Pragma("unroll")                                                           \
    for (int g = 0; g < 8; g++) {                                               \
      unsigned ag = ra + (BB) + g * 1184;                                       \
      asm volatile("ds_read_b64_tr_b16 %0, %1" : "=v"(a0[g]) : "v"(ag));        \
      asm volatile("ds_read_b64_tr_b16 %0, %1 offset:144" : "=v"(a1[g]) : "v"(ag)); \
    }                                                                           \
    asm volatile("s_waitcnt lgkmcnt(0)" ::: "memory");                          \
    __builtin_amdgcn_sched_barrier(0);                                          \
    _Pragma("unroll")                                                           \
    for (int mf = 0; mf < 8; mf++) {                                            \
      union { uint2 u[2]; bf16x8 v; } af;                                       \
      af.u[0] = a0[mf]; af.u[1] = a1[mf];                                       \
      _Pragma("unroll")                                                         \
      for (int nf = 0; nf < 4; nf++)                                            \
        acc[mf][nf] = __builtin_amdgcn_mfma_f32_16x16x32_bf16(                  \
            af.v, *(const bf16x8*)&bvC[nf], acc[mf][nf], 0, 0, 0);              \
    }                                                                           \
  }

__global__ __launch_bounds__(256, 2) void k_einsum_tr(
    const unsigned short* __restrict__ Ep, const float* __restrict__ x,
    float* __restrict__ out) {
    extern __shared__ unsigned short xs[];    // 2 x 9472 B
    int t = threadIdx.x;
    int b = blockIdx.y;
    int d0 = blockIdx.x * 128;
    int lane = t & 63, w = t >> 6;
    int l15 = lane & 15, lq = lane >> 4;

    // staging mapping: thread owns (kblk = t>>5, d-quad = t&31); 4 k-rows via s
    int dq = t & 31;                          // d = 4*dq .. 4*dq+3
    int jb = (t >> 5) * 4;                    // k base within tile (k = jb+s)
    const float* xb = x + ((size_t)b * 256) * 768 + d0 + 4 * dq;
    // LDS write byte offset: elem = (dq>>2)*592 + (jb>>2)*72 + s*16 + (dq&3)*4
    unsigned wbyte = (unsigned)(((dq >> 2) * 592 + (jb >> 2) * 72 + (dq & 3) * 4) * 2);
    // tr-read per-lane addr: lane c=l15 of group lq fetches subtile elems [4c,4c+3]
    unsigned ra = (unsigned)(lq * 288 + l15 * 8);

    // Ep row pointer for this wave's i-range (n0 = w*64); B-frag: lane holds
    // Ep[(n0+nf*16+l15)][kt*32+lq*8 .. +7] -> 16B contiguous, L2-hot
    const unsigned short* eprow = Ep + (((w * 64 + l15) << 8) + lq * 8);

    f32x4 acc[8][4];
    #pragma unroll
    for (int mf = 0; mf < 8; mf++)
        #pragma unroll
        for (int nf = 0; nf < 4; nf++)
            #pragma unroll
            for (int e = 0; e < 4; e++) acc[mf][nf][e] = 0.f;

    // prologue: tile 0 x-regs + kt=0 Ep frags
    float4 xr[4];
    #pragma unroll
    for (int s = 0; s < 4; s++) xr[s] = *(const float4*)(xb + (size_t)(jb + s) * 768);
    uint4 bv0[4], bv1[4];
    #pragma unroll
    for (int nf = 0; nf < 4; nf++) bv0[nf] = *(const uint4*)(eprow + (nf << 12));

    #pragma unroll
    for (int k2 = 0; k2 < 4; k2++) {
        EIN_BODY(2 * k2,     0,         bv0, bv1)
        EIN_BODY(2 * k2 + 1, EINS_BUFB, bv1, bv0)
    }

    // epilogue: D rows = d (lq*4+reg -> 4 consecutive d), cols = i (l15)
    float* ob = out + ((size_t)b * 256) * 768 + d0;
    #pragma unroll
    for (int mf = 0; mf < 8; mf++) {
        #pragma unroll
        for (int nf = 0; nf < 4; nf++) {
            int i = w * 64 + nf * 16 + l15;
            int d = mf * 16 + lq * 4;
            *(float4*)(ob + (size_t)i * 768 + d) = *(float4*)&acc[mf][nf];
        }
    }
}

extern "C" void kernel_launch(void* const* d_in, const int* in_sizes, int n_in,
                              void* d_out, int out_size, void* d_ws, size_t ws_size,
                              hipStream_t stream) {
    const float* x   = (const float*)d_in[0];
    const float* cf  = (const float*)d_in[1];
    const float* ctx = (const float*)d_in[2];
    const float* w1  = (const float*)d_in[3];
    const float* b1  = (const float*)d_in[4];
    const float* w2  = (const float*)d_in[5];
    const float* b2  = (const float*)d_in[6];
    const int*   co  = (const int*)d_in[7];
    const int*   ic  = (const int*)d_in[8];
    float* out = (float*)d_out;

    float* ws   = (float*)d_ws;
    float* vsn  = ws;                        // 196608
    float* csn  = vsn + 196608;              // 196608
    float* a    = csn + 196608;              // 98304
    float* vs   = a + 98304;                 // 65536
    float* cs   = vs + 65536;                // 65536
    float* e1   = cs + 65536;                // 65536
    float* ss   = e1 + 65536;                // 65536
    float* sc   = ss + 65536;                // 65536
    float* E    = sc + 65536;                // 65536
    float* topv = E + 65536;                 // 1280
    int*   topi = (int*)(topv + 1280);       // 1280
    float* partials = (float*)(topi + 1280); // 256
    unsigned short* Ep = (unsigned short*)(partials + 256);  // 65536 bf16

    k_stage1<<<672, 256, 0, stream>>>(cf, ctx, vsn, csn, w1, a, co, topv, topi);
    k_gram2<<<128, 256, 0, stream>>>(vsn, csn, vs, cs);
    k_stage3<<<320, 256, 0, stream>>>(a, b1, w2, b2, vs, cs, ic, e1, co, ss, sc);
    k_assemble<<<256, 256, 0, stream>>>(co, vs, cs, e1, ss, sc, topv, topi, E, partials);
    k_ep<<<64, 256, 0, stream>>>(E, partials, Ep);
    k_einsum_tr<<<dim3(6, BATCH), 256, 2 * EINS_BUFB, stream>>>(Ep, x, out);
}

// Round 3
// 288.183 us; speedup vs baseline: 1.0074x; 1.0074x over previous
//
#include <hip/hip_runtime.h>
#include <hip/hip_bf16.h>
#include <math.h>

#define N 256
#define D 768
#define BATCH 128

typedef float f32x4 __attribute__((ext_vector_type(4)));
typedef short bf16x8 __attribute__((ext_vector_type(8)));

// RNE fp32 -> bf16 (no NaN inputs in this problem)
static __device__ __forceinline__ unsigned short f2bf(float f) {
    unsigned int u = __float_as_uint(f);
    u += 0x7fffu + ((u >> 16) & 1u);
    return (unsigned short)(u >> 16);
}
static __device__ __forceinline__ unsigned int pack2bf(float lo, float hi) {
    unsigned int a = __float_as_uint(lo);
    unsigned int b = __float_as_uint(hi);
    a += 0x7fffu + ((a >> 16) & 1u);
    b += 0x7fffu + ((b >> 16) & 1u);
    return (a >> 16) | (b & 0xffff0000u);
}

// ---------------- Stage 1 (fused): norm (512 blk) + a2 (96 blk) + topk (64 blk)
__global__ void k_stage1(const float* __restrict__ cf, const float* __restrict__ ctx,
                         float* __restrict__ vsn, float* __restrict__ csn,
                         const float* __restrict__ w1, float* __restrict__ a,
                         const int* __restrict__ co, float* __restrict__ topv,
                         int* __restrict__ topi) {
    __shared__ float sm[2 * 64 * 33];        // union: norm red[256] / a2 Ci+Wj
    int bx = blockIdx.x;
    int t = threadIdx.x;                     // 256
    if (bx < 512) {
        // ---- norm ----
        int row = bx;
        const float* src;
        float* dst;
        if (row < N) { src = cf  + row * D;       dst = vsn + row * D; }
        else         { src = ctx + (row - N) * D; dst = csn + (row - N) * D; }
        float s = 0.f;
        for (int d = t; d < D; d += 256) { float v = src[d]; s += v * v; }
        float* red = sm;
        red[t] = s; __syncthreads();
        for (int off = 128; off > 0; off >>= 1) {
            if (t < off) red[t] += red[t + off];
            __syncthreads();
        }
        float inv = 1.0f / sqrtf(red[0]);
        for (int d = t; d < D; d += 256) dst[d] = src[d] * inv;
    } else if (bx < 608) {
        // ---- a = cf @ w1, 32x32 tiles ----
        int bi = bx - 512;
        int i0 = (bi / 12) * 32, j0 = (bi % 12) * 32;
        float (*Ci)[33] = (float(*)[33])sm;
        float (*Wj)[33] = (float(*)[33])(sm + 64 * 33);
        int tx = t & 15, ty = t >> 4;
        float a00 = 0.f, a01 = 0.f, a10 = 0.f, a11 = 0.f;
        for (int k0 = 0; k0 < 768; k0 += 64) {
            #pragma unroll
            for (int s = 0; s < 8; s++) {
                int idx = s * 256 + t;
                int row = idx >> 6, kc = idx & 63;
                Ci[kc][row] = cf[(i0 + row) * 768 + k0 + kc];
                int kr = idx >> 5, col = idx & 31;
                Wj[kr][col] = w1[(k0 + kr) * 384 + j0 + col];
            }
            __syncthreads();
            #pragma unroll 4
            for (int kk = 0; kk < 64; kk++) {
                float iv0 = Ci[kk][ty * 2], iv1 = Ci[kk][ty * 2 + 1];
                float jv0 = Wj[kk][tx * 2], jv1 = Wj[kk][tx * 2 + 1];
                a00 += iv0 * jv0; a01 += iv0 * jv1;
                a10 += iv1 * jv0; a11 += iv1 * jv1;
            }
            __syncthreads();
        }
        a[(i0 + ty * 2)     * 384 + j0 + tx * 2]     = a00;
        a[(i0 + ty * 2)     * 384 + j0 + tx * 2 + 1] = a01;
        a[(i0 + ty * 2 + 1) * 384 + j0 + tx * 2]     = a10;
        a[(i0 + ty * 2 + 1) * 384 + j0 + tx * 2 + 1] = a11;
    } else {
        // ---- top-5, one wave per row ----
        int lane = t & 63;
        int row = (bx - 608) * 4 + (t >> 6);
        int4 v4 = *(const int4*)(co + row * 256 + lane * 4);
        int key[4];
        key[0] = v4.x * 256 + (255 - (lane * 4 + 0));
        key[1] = v4.y * 256 + (255 - (lane * 4 + 1));
        key[2] = v4.z * 256 + (255 - (lane * 4 + 2));
        key[3] = v4.w * 256 + (255 - (lane * 4 + 3));
        for (int r = 0; r < 5; r++) {
            int best = key[0];
            #pragma unroll
            for (int e = 1; e < 4; e++) best = max(best, key[e]);
            #pragma unroll
            for (int off = 32; off > 0; off >>= 1) best = max(best, __shfl_xor(best, off, 64));
            int kidx = 255 - (best & 255);
            int val = best >> 8;
            if (lane == 0) { topv[row * 5 + r] = (float)val; topi[row * 5 + r] = kidx; }
            if ((kidx >> 2) == lane) key[kidx & 3] = -1;
        }
    }
}

// ---------------- K3: vs/cs gram, coalesced LDS-tiled (32x32 tiles) ---------
__global__ void k_gram2(const float* __restrict__ vsn, const float* __restrict__ csn,
                        float* __restrict__ vs, float* __restrict__ cs) {
    int bx = blockIdx.x;                 // 0..127
    const float* S = (bx >= 64) ? csn : vsn;
    float* O       = (bx >= 64) ? cs  : vs;
    int bi = bx & 63;
    int i0 = (bi >> 3) * 32, j0 = (bi & 7) * 32;
    __shared__ float Li[64][33], Lj[64][33];
    int t = threadIdx.x;
    int tx = t & 15, ty = t >> 4;
    float a00 = 0.f, a01 = 0.f, a10 = 0.f, a11 = 0.f;
    for (int k0 = 0; k0 < 768; k0 += 64) {
        #pragma unroll
        for (int s = 0; s < 8; s++) {
            int idx = s * 256 + t;
            int row = idx >> 6, kc = idx & 63;
            Li[kc][row] = S[(i0 + row) * 768 + k0 + kc];
            Lj[kc][row] = S[(j0 + row) * 768 + k0 + kc];
        }
        __syncthreads();
        #pragma unroll 4
        for (int kk = 0; kk < 64; kk++) {
            float iv0 = Li[kk][ty * 2], iv1 = Li[kk][ty * 2 + 1];
            float jv0 = Lj[kk][tx * 2], jv1 = Lj[kk][tx * 2 + 1];
            a00 += iv0 * jv0; a01 += iv0 * jv1;
            a10 += iv1 * jv0; a11 += iv1 * jv1;
        }
        __syncthreads();
    }
    O[(i0 + ty * 2)     * 256 + j0 + tx * 2]     = a00;
    O[(i0 + ty * 2)     * 256 + j0 + tx * 2 + 1] = a01;
    O[(i0 + ty * 2 + 1) * 256 + j0 + tx * 2]     = a10;
    O[(i0 + ty * 2 + 1) * 256 + j0 + tx * 2 + 1] = a11;
}

// ---------------- Stage 3 (fused): e1t (256 blk) + shared2 (64 blk) --------
__global__ void k_stage3(const float* __restrict__ a, const float* __restrict__ b1,
                         const float* __restrict__ w2, const float* __restrict__ b2,
                         const float* __restrict__ vs, const float* __restrict__ cs,
                         const int* __restrict__ ic, float* __restrict__ e1,
                         const int* __restrict__ co, float* __restrict__ ss,
                         float* __restrict__ sc) {
    __shared__ float sm[12800];          // 51200 B: e1t ai/ajm/sw2 OR shared2 tiles
    int bx = blockIdx.x;
    int t = threadIdx.x;
    if (bx < 256) {
        // ---- e1 pair-tiled 16x16 ----
        int i0 = (bx >> 4) * 16, j0 = (bx & 15) * 16;
        float (*ai)[388]  = (float(*)[388])sm;
        float (*ajm)[388] = (float(*)[388])(sm + 16 * 388);
        float* sw2 = sm + 2 * 16 * 388;
        for (int idx = t; idx < 16 * 96; idx += 256) {
            int r = idx / 96, c = (idx % 96) * 4;
            *(float4*)&ai[r][c] = *(const float4*)(a + (i0 + r) * 384 + c);
            float4 u  = *(const float4*)(a + (j0 + r) * 384 + c);
            float4 bb = *(const float4*)(b1 + c);
            u.x -= bb.x; u.y -= bb.y; u.z -= bb.z; u.w -= bb.w;
            *(float4*)&ajm[r][c] = u;
        }
        for (int k = t; k < 384; k += 256) sw2[k] = w2[k];
        __syncthreads();
        int tx = t & 15, ty = t >> 4;
        float s = 0.f;
        #pragma unroll 4
        for (int k4 = 0; k4 < 96; k4++) {
            float4 xv = *(const float4*)&ai[ty][k4 * 4];
            float4 yv = *(const float4*)&ajm[tx][k4 * 4];
            float4 wv = *(const float4*)&sw2[k4 * 4];
            s += fmaxf(xv.x - yv.x, 0.f) * wv.x;
            s += fmaxf(xv.y - yv.y, 0.f) * wv.y;
            s += fmaxf(xv.z - yv.z, 0.f) * wv.z;
            s += fmaxf(xv.w - yv.w, 0.f) * wv.w;
        }
        int i = i0 + ty, j = j0 + tx;
        float sig = 1.0f / (1.0f + expf(-(s + b2[0])));
        float comb = 0.7f * vs[i * 256 + j] + 0.3f * cs[i * 256 + j];
        float ci = (float)ic[i], cj = (float)ic[j];
        float mn = fminf(ci, cj), mx = fmaxf(ci, cj);
        float ratio = mn / fmaxf(mx, 1.0f);
        e1[i * 256 + j] = comb * sig * ratio;
    } else {
        // ---- shared_sum/cnt 32x32 tiles ----
        int bi = bx - 256;
        int i0 = (bi >> 3) * 32, j0 = (bi & 7) * 32;
        float (*Mi)[33] = (float(*)[33])sm;
        float (*Ai)[33] = (float(*)[33])(sm + 2112);
        float (*Mj)[33] = (float(*)[33])(sm + 4224);
        float (*Aj)[33] = (float(*)[33])(sm + 6336);
        int tx = t & 15, ty = t >> 4;
        float s00=0.f,s01=0.f,s10=0.f,s11=0.f;
        float c00=0.f,c01=0.f,c10=0.f,c11=0.f;
        for (int k0 = 0; k0 < 256; k0 += 64) {
            #pragma unroll
            for (int s = 0; s < 8; s++) {
                int idx = s * 256 + t;
                int row = idx >> 6, kc = idx & 63;
                int civ = co[(i0 + row) * 256 + k0 + kc];
                float aa = civ > 50 ? 1.f : 0.f;
                Ai[kc][row] = aa;
                Mi[kc][row] = aa * vs[(i0 + row) * 256 + k0 + kc];
                int cjv = co[(j0 + row) * 256 + k0 + kc];
                float ab = cjv > 50 ? 1.f : 0.f;
                Aj[kc][row] = ab;
                Mj[kc][row] = ab * vs[(j0 + row) * 256 + k0 + kc];
            }
            __syncthreads();
            #pragma unroll 4
            for (int kk = 0; kk < 64; kk++) {
                float mi0 = Mi[kk][ty*2], mi1 = Mi[kk][ty*2+1];
                float ai0 = Ai[kk][ty*2], ai1 = Ai[kk][ty*2+1];
                float mj0 = Mj[kk][tx*2], mj1 = Mj[kk][tx*2+1];
                float aj0 = Aj[kk][tx*2], aj1 = Aj[kk][tx*2+1];
                s00 += mi0*mj0; s01 += mi0*mj1; s10 += mi1*mj0; s11 += mi1*mj1;
                c00 += ai0*aj0; c01 += ai0*aj1; c10 += ai1*aj0; c11 += ai1*aj1;
            }
            __syncthreads();
        }
        ss[(i0+ty*2)  *256 + j0+tx*2]   = s00; ss[(i0+ty*2)  *256 + j0+tx*2+1] = s01;
        ss[(i0+ty*2+1)*256 + j0+tx*2]   = s10; ss[(i0+ty*2+1)*256 + j0+tx*2+1] = s11;
        sc[(i0+ty*2)  *256 + j0+tx*2]   = c00; sc[(i0+ty*2)  *256 + j0+tx*2+1] = c01;
        sc[(i0+ty*2+1)*256 + j0+tx*2]   = c10; sc[(i0+ty*2+1)*256 + j0+tx*2+1] = c11;
    }
}

// ---------------- K7: assemble E (tiered), zero diag, per-row max -----------
__global__ void k_assemble(const int* __restrict__ co, const float* __restrict__ vs,
                           const float* __restrict__ cs, const float* __restrict__ e1,
                           const float* __restrict__ ss, const float* __restrict__ sc,
                           const float* __restrict__ topv, const int* __restrict__ topi,
                           float* __restrict__ E, float* __restrict__ partials) {
    int i = blockIdx.x, j = threadIdx.x;
    int cij = co[i * 256 + j];
    float e;
    if (i == j) {
        e = 0.f;
    } else if (cij > 50) {
        e = e1[i * 256 + j];
    } else if (cij > 10) {
        float conf = (float)cij / 50.0f;
        float comb = 0.7f * vs[i * 256 + j] + 0.3f * cs[i * 256 + j];
        float cnt = sc[i * 256 + j];
        float avg = ss[i * 256 + j] / fmaxf(cnt, 1.f);
        e = (cnt > 0.f) ? conf * comb + (1.f - conf) * avg : conf * comb;
    } else {
        float tvi[5], tvj[5]; int tii[5], tij[5];
        #pragma unroll
        for (int k = 0; k < 5; k++) {
            tvi[k] = topv[i * 5 + k]; tii[k] = topi[i * 5 + k];
            tvj[k] = topv[j * 5 + k]; tij[k] = topi[j * 5 + k];
        }
        float trans = 0.f, tot = 0.f;
        #pragma unroll
        for (int k = 0; k < 5; k++) {
            if (!(tvi[k] > 10.f)) continue;
            float vin_i = vs[i * 256 + tii[k]];
            #pragma unroll
            for (int l = 0; l < 5; l++) {
                if (!(tvj[l] > 10.f)) continue;
                int cc = co[tii[k] * 256 + tij[l]];
                if (cc <= 0) continue;
                float w = tvi[k] * tvj[l] / 50.f;
                float sim = vin_i * vs[j * 256 + tij[l]] * vs[tii[k] * 256 + tij[l]];
                trans += w * sim; tot += w;
            }
        }
        e = (tot > 0.f) ? trans / tot : 0.1f * cs[i * 256 + j];
    }
    E[i * 256 + j] = e;
    __shared__ float red[256];
    red[j] = e; __syncthreads();
    for (int off = 128; off > 0; off >>= 1) {
        if (j < off) red[j] = fmaxf(red[j], red[j + off]);
        __syncthreads();
    }
    if (j == 0) partials[i] = red[0];
}

// ---------------- K8: Ep = bf16(I + s*E), s = 1/max (fused scale) -----------
__global__ void k_ep(const float* __restrict__ E, const float* __restrict__ partials,
                     unsigned short* __restrict__ Ep) {
    __shared__ float red[256];
    int t = threadIdx.x;
    red[t] = partials[t]; __syncthreads();
    for (int off = 128; off > 0; off >>= 1) {
        if (t < off) red[t] = fmaxf(red[t], red[t + off]);
        __syncthreads();
    }
    float mx = red[0];
    float s = (mx > 0.f) ? 1.0f / mx : 1.0f;
    int base = (blockIdx.x * 256 + t) * 4;
    float4 e4 = *(const float4*)(E + base);
    float ev[4] = {e4.x, e4.y, e4.z, e4.w};
    unsigned short o[4];
    #pragma unroll
    for (int q = 0; q < 4; q++) {
        int g = base + q;
        float v = s * ev[q] + (((g >> 8) == (g & 255)) ? 1.0f : 0.0f);
        o[q] = f2bf(v);
    }
    uint2 w;
    w.x = (unsigned int)o[0] | ((unsigned int)o[1] << 16);
    w.y = (unsigned int)o[2] | ((unsigned int)o[3] << 16);
    *(uint2*)(Ep + base) = w;
}

// ---------------- K9: out[b,:,dtile] = Ep @ x[b,:,dtile]  (bf16 MFMA) -------
// r2 post-mortem: stall-bound (MfmaUtil 5.9 / VALU 4.4 / HBM 25% -- all idle).
// x prefetch distance was 1 body (~350cy) vs ~900cy HBM latency, and acc[8][4]
// (128 regs) capped residency at 2 blocks/CU. This version:
//  * d-tile 64: acc[4][4]=64 regs -> ~3 blocks/CU; grid dim3(12,128)=1536
//    blocks = exactly 2 rounds of 3/CU (no ragged tail). LDS 9.5KB dbuf.
//  * 2-deep x prefetch in regs (xA/xB): load-to-use = 2 bodies (~700cy).
//  * Ep bv prefetch issued BEFORE x prefetch each body -> MFMA's wait is a
//    counted vmcnt that leaves the deep x loads in flight (vmcnt is
//    issue-ordered; needed-sooner must be issued first).
// Addressing identical to r2-verified formulas, 4 dblks instead of 8:
//  LDS layout [dblk(592e)][kblk(72e)][4k][16d]; tr_b16 lane addr = base+c*8;
//  a1 at +144B (next kblk); group lq at lq*288; dblk stride 1184B.
#define EINS_BUFB 4736   // bytes per k-tile buffer: 4 dblk * 592 elems * 2B

#define EIN_BODY(KT, BB, XR, bvC, bvN)                                          \
  {                                                                             \
    uint4 pv;                                                                   \
    pv.x = pack2bf(XR[0].x, XR[0].y);                                           \
    pv.y = pack2bf(XR[0].z, XR[0].w);                                           \
    pv.z = pack2bf(XR[1].x, XR[1].y);                                           \
    pv.w = pack2bf(XR[1].z, XR[1].w);                                           \
    *(uint4*)((char*)xs + (BB) + wbyte) = pv;                                   \
    __syncthreads();                                                            \
    if ((KT) < 7) {                                                             \
      _Pragma("unroll")                                                         \
      for (int nf = 0; nf < 4; nf++)                                            \
        bvN[nf] = *(const uint4*)(eprow + (nf << 12) + ((KT) + 1) * 32);        \
    }                                                                           \
    if ((KT) < 6) {                                                             \
      const float* xn = xb + (size_t)((KT) + 2) * 32 * 768;                     \
      XR[0] = *(const float4*)xn;                                               \
      XR[1] = *(const float4*)(xn + 4);                                         \
    }                                                                           \
    uint2 a0[4], a1[4];                                                         \
    _Pragma("unroll")                                                           \
    for (int g = 0; g < 4; g++) {                                               \
      unsigned ag = ra + (BB) + g * 1184;                                       \
      asm volatile("ds_read_b64_tr_b16 %0, %1" : "=v"(a0[g]) : "v"(ag));        \
      asm volatile("ds_read_b64_tr_b16 %0, %1 offset:144" : "=v"(a1[g]) : "v"(ag)); \
    }                                                                           \
    asm volatile("s_waitcnt lgkmcnt(0)" ::: "memory");                          \
    __builtin_amdgcn_sched_barrier(0);                                          \
    _Pragma("unroll")                                                           \
    for (int mf = 0; mf < 4; mf++) {                                            \
      union { uint2 u[2]; bf16x8 v; } af;                                       \
      af.u[0] = a0[mf]; af.u[1] = a1[mf];                                       \
      _Pragma("unroll")                                                         \
      for (int nf = 0; nf < 4; nf++)                                            \
        acc[mf][nf] = __builtin_amdgcn_mfma_f32_16x16x32_bf16(                  \
            af.v, *(const bf16x8*)&bvC[nf], acc[mf][nf], 0, 0, 0);              \
    }                                                                           \
  }

__global__ __launch_bounds__(256, 3) void k_einsum_tr(
    const unsigned short* __restrict__ Ep, const float* __restrict__ x,
    float* __restrict__ out) {
    extern __shared__ unsigned short xs[];    // 2 x 4736 B
    int t = threadIdx.x;
    int b = blockIdx.y;
    int d0 = blockIdx.x * 64;
    int lane = t & 63, w = t >> 6;
    int l15 = lane & 15, lq = lane >> 4;

    // staging: thread owns (k-row kr = t>>3, d-octet dh = t&7) -> 32B contig
    int dh = t & 7, kr = t >> 3;
    const float* xb = x + ((size_t)b * 256) * 768 + (size_t)kr * 768 + d0 + dh * 8;
    // LDS write byte: dblk(dh>>1)*1184 + kblk(kr>>2)*144 + (kr&3)*32 + (dh&1)*16
    unsigned wbyte = (unsigned)((dh >> 1) * 1184 + (kr >> 2) * 144 + (kr & 3) * 32 + (dh & 1) * 16);
    // tr-read per-lane addr: lane c=l15 of group lq fetches subtile elems [4c,4c+3]
    unsigned ra = (unsigned)(lq * 288 + l15 * 8);

    // Ep B-frag: lane holds Ep[(w*64+nf*16+l15)][kt*32+lq*8 .. +7], L2-hot
    const unsigned short* eprow = Ep + (((w * 64 + l15) << 8) + lq * 8);

    f32x4 acc[4][4];
    #pragma unroll
    for (int mf = 0; mf < 4; mf++)
        #pragma unroll
        for (int nf = 0; nf < 4; nf++)
            #pragma unroll
            for (int e = 0; e < 4; e++) acc[mf][nf][e] = 0.f;

    // prologue: x tiles 0,1 + Ep frags tile 0
    float4 xA[2], xB[2];
    xA[0] = *(const float4*)xb;
    xA[1] = *(const float4*)(xb + 4);
    xB[0] = *(const float4*)(xb + 32 * 768);
    xB[1] = *(const float4*)(xb + 32 * 768 + 4);
    uint4 bv0[4], bv1[4];
    #pragma unroll
    for (int nf = 0; nf < 4; nf++) bv0[nf] = *(const uint4*)(eprow + (nf << 12));

    #pragma unroll
    for (int k2 = 0; k2 < 4; k2++) {
        EIN_BODY(2 * k2,     0,         xA, bv0, bv1)
        EIN_BODY(2 * k2 + 1, EINS_BUFB, xB, bv1, bv0)
    }

    // epilogue: D rows = d (lq*4+reg -> 4 consecutive d), cols = i (l15)
    float* ob = out + ((size_t)b * 256) * 768 + d0;
    #pragma unroll
    for (int mf = 0; mf < 4; mf++) {
        #pragma unroll
        for (int nf = 0; nf < 4; nf++) {
            int i = w * 64 + nf * 16 + l15;
            int d = mf * 16 + lq * 4;
            *(float4*)(ob + (size_t)i * 768 + d) = *(float4*)&acc[mf][nf];
        }
    }
}

extern "C" void kernel_launch(void* const* d_in, const int* in_sizes, int n_in,
                              void* d_out, int out_size, void* d_ws, size_t ws_size,
                              hipStream_t stream) {
    const float* x   = (const float*)d_in[0];
    const float* cf  = (const float*)d_in[1];
    const float* ctx = (const float*)d_in[2];
    const float* w1  = (const float*)d_in[3];
    const float* b1  = (const float*)d_in[4];
    const float* w2  = (const float*)d_in[5];
    const float* b2  = (const float*)d_in[6];
    const int*   co  = (const int*)d_in[7];
    const int*   ic  = (const int*)d_in[8];
    float* out = (float*)d_out;

    float* ws   = (float*)d_ws;
    float* vsn  = ws;                        // 196608
    float* csn  = vsn + 196608;              // 196608
    float* a    = csn + 196608;              // 98304
    float* vs   = a + 98304;                 // 65536
    float* cs   = vs + 65536;                // 65536
    float* e1   = cs + 65536;                // 65536
    float* ss   = e1 + 65536;                // 65536
    float* sc   = ss + 65536;                // 65536
    float* E    = sc + 65536;                // 65536
    float* topv = E + 65536;                 // 1280
    int*   topi = (int*)(topv + 1280);       // 1280
    float* partials = (float*)(topi + 1280); // 256
    unsigned short* Ep = (unsigned short*)(partials + 256);  // 65536 bf16

    k_stage1<<<672, 256, 0, stream>>>(cf, ctx, vsn, csn, w1, a, co, topv, topi);
    k_gram2<<<128, 256, 0, stream>>>(vsn, csn, vs, cs);
    k_stage3<<<320, 256, 0, stream>>>(a, b1, w2, b2, vs, cs, ic, e1, co, ss, sc);
    k_assemble<<<256, 256, 0, stream>>>(co, vs, cs, e1, ss, sc, topv, topi, E, partials);
    k_ep<<<64, 256, 0, stream>>>(E, partials, Ep);
    k_einsum_tr<<<dim3(12, BATCH), 256, 2 * EINS_BUFB, stream>>>(Ep, x, out);
}